// Round 18
// baseline (114.597 us; speedup 1.0000x reference)
//
#include <hip/hip_runtime.h>
#include <hip/hip_bf16.h>
#include <cstdint>
#include <cstddef>

// SelfAttention fused block, MI355X gfx950.
// Round 17: unbundle round 16. The ones-MFMA lsum REGRESSED (f32x16 ls state
// +48 live VGPRs at the 128-cap -> compiler shuffling, VALUBusy 30.8->36).
// Keep ONLY the live-state-neutral half: Q-prescale (0.125/ln2 folded into
// Wqkv q-cols + q-bias) -> attn body computes P = exp2f(z) bare (deletes
// 32 VALU/body vs round-15's __expf(z*0.125)). Attn body otherwise VERBATIM
// round-15 (f32x4 lsv, 65-float merge rows, shfl reduce; proven 41.9us).
// GEMMs: dbuf 2-phase (proven, -7.6us). Base: round-15 = 106.8us measured.
// Ledger: attn 41.9 (R15) | ones-MFMA 48.1 | 4-way 63 | uniform 64 | 3PF BUG
//         QKV dbuf ~37 | 2-barrier 43.6 | BK64swz 56 | BN64 61 | 8ph 68.7

using bf16 = __hip_bfloat16;
typedef __attribute__((ext_vector_type(8))) short short8;
typedef __attribute__((ext_vector_type(4))) float f32x4;
typedef __attribute__((ext_vector_type(16))) float f32x16;
typedef __attribute__((ext_vector_type(4))) unsigned int u32x4;

#define QSCALE 0.18033688f  // 0.125 / ln(2): P = exp2(Qs.K) = exp(0.125 Q.K)

__device__ __forceinline__ unsigned short f2b(float f) {
    bf16 h = __float2bfloat16(f);
    return *reinterpret_cast<unsigned short*>(&h);
}

__device__ __forceinline__ void async16(const void* g, void* l) {
    __builtin_amdgcn_global_load_lds(
        (const __attribute__((address_space(1))) void*)g,
        (__attribute__((address_space(3))) void*)l, 16, 0, 0);
}

// ---------------- K1: fused prep: x fp32->bf16, Wqkv^T (q-scaled), Wo^T ------
__global__ __launch_bounds__(256) void prep_kernel(
    const float* __restrict__ x, bf16* __restrict__ x_bf,
    const float* __restrict__ Wqkv, bf16* __restrict__ wqkv_t,
    const float* __restrict__ Wo, bf16* __restrict__ wo_t) {
    const int bid = blockIdx.x;
    const int tid = threadIdx.x;
    if (bid < 4096) {  // cvt: 1M float4
        const int i = bid * 256 + tid;
        const float4 v = reinterpret_cast<const float4*>(x)[i];
        ushort4 o;
        o.x = f2b(v.x); o.y = f2b(v.y); o.z = f2b(v.z); o.w = f2b(v.w);
        reinterpret_cast<ushort4*>(x_bf)[i] = o;
        return;
    }
    __shared__ float tile[32][33];
    const float* in;
    bf16* out;
    int K, N, n0, k0;
    if (bid < 4096 + 3072) {
        const int blk = bid - 4096;
        in = Wqkv; out = wqkv_t; K = 1024; N = 3072;
        n0 = (blk % 96) * 32; k0 = (blk / 96) * 32;
    } else {
        const int blk = bid - 7168;
        in = Wo; out = wo_t; K = 1024; N = 1024;
        n0 = (blk % 32) * 32; k0 = (blk / 32) * 32;
    }
    // q-part of Wqkv (output cols 0..1023) pre-scaled by QSCALE
    const float scl =
        (bid >= 4096 && bid < 7168 && ((bid - 4096) % 96) < 32) ? QSCALE : 1.0f;
    const int tx = tid & 31, ty = tid >> 5;  // (32,8)
    #pragma unroll
    for (int i = 0; i < 32; i += 8)
        tile[ty + i][tx] = in[(size_t)(k0 + ty + i) * N + n0 + tx];
    __syncthreads();
    #pragma unroll
    for (int i = 0; i < 32; i += 8)
        out[(size_t)(n0 + ty + i) * K + k0 + tx] =
            __float2bfloat16(tile[tx][ty + i] * scl);
}

// --- K3/K5: 128xBN BK=32 linear-LDS bf16 MFMA GEMM, dbuf prefetch, B^T in ----
template <int EPI, int BN>
__global__ __launch_bounds__(256) void gemm_bt(
    const bf16* __restrict__ A,   // [M][K] bf16
    const bf16* __restrict__ Bt,  // [N][K] bf16
    const float* __restrict__ bias,  // [N] fp32
    float* __restrict__ Cf,          // EPI==0: [M][N] fp32
    bf16* __restrict__ qd, bf16* __restrict__ kd, bf16* __restrict__ vtd,
    int M, int N, int K) {
    constexpr int NFR = BN / 32;  // B frags per wave (wave n-span = BN/2)
    __shared__ bf16 As[2][128 * 32];
    __shared__ bf16 Bs[2][BN * 32];
    const int t = threadIdx.x;
    const int lane = t & 63;
    const int lr = lane & 15, lg = lane >> 4;
    const int wave = t >> 6;
    const int wr = wave >> 1, wc = wave & 1;  // 2x2 waves
    const int m0 = blockIdx.x * 128, n0 = blockIdx.y * BN;

    const bf16* aSrc = A + (size_t)(m0 + (t >> 2)) * K + (t & 3) * 8;
    const bf16* bSrc = Bt + (size_t)(n0 + (t >> 2)) * K + (t & 3) * 8;
    const size_t rowStep = (size_t)64 * K;

    auto stage = [&](int buf, int k0) {
        async16(aSrc + k0, &As[buf][t * 8]);
        async16(aSrc + rowStep + k0, &As[buf][2048 + t * 8]);
        async16(bSrc + k0, &Bs[buf][t * 8]);
        if constexpr (BN == 128)
            async16(bSrc + rowStep + k0, &Bs[buf][2048 + t * 8]);
    };

    f32x4 acc[4][NFR] = {};

    stage(0, 0);
    __syncthreads();

    int cur = 0;
    for (int k0 = 0; k0 < K; k0 += 32) {
        if (k0 + 32 < K) stage(cur ^ 1, k0 + 32);
        short8 af[4], bfr[NFR];
        #pragma unroll
        for (int i = 0; i < 4; ++i)
            af[i] = *reinterpret_cast<const short8*>(
                &As[cur][(wr * 64 + i * 16 + lr) * 32 + lg * 8]);
        #pragma unroll
        for (int i = 0; i < NFR; ++i)
            bfr[i] = *reinterpret_cast<const short8*>(
                &Bs[cur][(wc * (BN / 2) + i * 16 + lr) * 32 + lg * 8]);
        #pragma unroll
        for (int mi = 0; mi < 4; ++mi)
            #pragma unroll
            for (int ni = 0; ni < NFR; ++ni)
                acc[mi][ni] = __builtin_amdgcn_mfma_f32_16x16x32_bf16(
                    af[mi], bfr[ni], acc[mi][ni], 0, 0, 0);
        __syncthreads();
        cur ^= 1;
    }

    #pragma unroll
    for (int mi = 0; mi < 4; ++mi) {
        #pragma unroll
        for (int ni = 0; ni < NFR; ++ni) {
            const int rowb = m0 + wr * 64 + mi * 16 + lg * 4;
            const int col = n0 + wc * (BN / 2) + ni * 16 + lr;
            if constexpr (EPI == 0) {
                #pragma unroll
                for (int r = 0; r < 4; ++r)
                    Cf[(size_t)(rowb + r) * N + col] = acc[mi][ni][r] + bias[col];
            } else {
                float bs = bias[col];
                if (col < 1024) bs *= QSCALE;  // q-bias matches scaled weights
                const int part = col >> 10;      // 0=q 1=k 2=v
                const int within = col & 1023;
                const int h = within >> 6, d = within & 63;
                const int b = rowb >> 11, s0 = rowb & 2047;
                const int bh = b * 16 + h;
                if (part == 2) {  // v^T: 4 consecutive s -> ushort4
                    ushort4 pk;
                    pk.x = f2b(acc[mi][ni][0] + bs);
                    pk.y = f2b(acc[mi][ni][1] + bs);
                    pk.z = f2b(acc[mi][ni][2] + bs);
                    pk.w = f2b(acc[mi][ni][3] + bs);
                    *reinterpret_cast<ushort4*>(
                        &vtd[((size_t)bh * 64 + d) * 2048 + s0]) = pk;
                } else {
                    bf16* dst = (part == 0) ? qd : kd;
                    #pragma unroll
                    for (int r = 0; r < 4; ++r)
                        dst[((size_t)bh * 2048 + s0 + r) * 64 + d] =
                            __float2bfloat16(acc[mi][ni][r] + bs);
                }
            }
        }
    }
}

// ---------------- K4: causal flash attention (R15 body + exp2) ---------------
// grid 512 (1-D, XCD-pinned), block 256 = 4 waves = 2 units x 2 parities.
// Decode: res=f&7, m=f>>3, grp=m>>4, bh=res+8*grp, bxr=m&15,
//   bx=(grp&2)?(15-bxr):bxr  -> co-resident pair (f, f+256) complementary
//   heavy+light per CU (measured-optimal; do not touch).
// Body identical to round-15 except P = exp2f(z) (Q pre-scaled by 0.125/ln2).
__global__ __launch_bounds__(256, 2) void attn_kernel(const bf16* __restrict__ q,
                                                      const bf16* __restrict__ k,
                                                      const bf16* __restrict__ vt,
                                                      bf16* __restrict__ o) {
    const int S = 2048;
    const int f = blockIdx.x;
    const int res = f & 7, m = f >> 3;
    const int grp = m >> 4;
    const int bh = res + 8 * grp;
    const int bxr = m & 15;
    const int bx = (grp & 2) ? (15 - bxr) : bxr;
    const int b = bh >> 4, h = bh & 15;
    const int w = threadIdx.x >> 6;
    const int u = w >> 1, par = w & 1;
    const int lane = threadIdx.x & 63;
    const int ln = lane & 31;
    const int hi = lane >> 5;
    const int P = 2 * (15 - bx) + u;     // 0..31
    const int qbaseA = P * 64;
    const int qbaseB = P * 64 + 32;

    const bf16* qp = q + (size_t)bh * S * 64;
    const bf16* kp = k + (size_t)bh * S * 64;
    const bf16* vp = vt + (size_t)bh * 64 * S;

    short8 qfA[4], qfB[4];
    #pragma unroll
    for (int i = 0; i < 4; ++i) {
        qfA[i] = *reinterpret_cast<const short8*>(
            &qp[(size_t)(qbaseA + ln) * 64 + i * 16 + hi * 8]);
        qfB[i] = *reinterpret_cast<const short8*>(
            &qp[(size_t)(qbaseB + ln) * 64 + i * 16 + hi * 8]);
    }

    f32x16 oA0 = {}, oA1 = {}, oB0 = {}, oB1 = {};
    f32x4 lsvA = {0.f, 0.f, 0.f, 0.f}, lsvB = {0.f, 0.f, 0.f, 0.f};

    short8 kA[4], kB[4], vA[4], vB[4];

    auto kload = [&](short8 (&kf)[4], int tile) {
        const bf16* base = &kp[(size_t)(tile * 32 + ln) * 64 + hi * 8];
        #pragma unroll
        for (int i = 0; i < 4; ++i)
            kf[i] = *reinterpret_cast<const short8*>(base + i * 16);
    };
    auto vload = [&](short8 (&vf)[4], int tile) {
        #pragma unroll
        for (int dblk = 0; dblk < 2; ++dblk)
            #pragma unroll
            for (int half = 0; half < 2; ++half)
                vf[dblk * 2 + half] = *reinterpret_cast<const short8*>(
                    &vp[(size_t)(dblk * 32 + ln) * S + tile * 32 + half * 16 +
                        hi * 8]);
    };

    auto body = [&](const short8 (&kf)[4], const short8 (&vf)[4],
                    const short8 (&qf)[4], f32x16& o0, f32x16& o1, f32x4& lsv,
                    bool diag) {
        f32x16 z0 = {}, z1 = {};
        z0 = __builtin_amdgcn_mfma_f32_32x32x16_bf16(kf[0], qf[0], z0, 0, 0, 0);
        z0 = __builtin_amdgcn_mfma_f32_32x32x16_bf16(kf[1], qf[1], z0, 0, 0, 0);
        z1 = __builtin_amdgcn_mfma_f32_32x32x16_bf16(kf[2], qf[2], z1, 0, 0, 0);
        z1 = __builtin_amdgcn_mfma_f32_32x32x16_bf16(kf[3], qf[3], z1, 0, 0, 0);
        const f32x16 z = z0 + z1;
        f32x16 pv;
        #pragma unroll
        for (int rr = 0; rr < 16; ++rr) {
            const int kreg = (rr & 3) + 8 * (rr >> 2) + 4 * hi;
            float e = exp2f(z[rr]);          // Q pre-scaled by 0.125/ln2
            if (diag && (kreg > ln)) e = 0.f;
            pv[rr] = e;
            lsv[rr & 3] += e;
        }
        unsigned a0, a1, b0, b1, c0, c1, d0, d1;
        asm("v_cvt_pk_bf16_f32 %0, %1, %2" : "=v"(a0) : "v"(pv[0]), "v"(pv[1]));
        asm("v_cvt_pk_bf16_f32 %0, %1, %2" : "=v"(a1) : "v"(pv[2]), "v"(pv[3]));
        asm("v_cvt_pk_bf16_f32 %0, %1, %2" : "=v"(b0) : "v"(pv[4]), "v"(pv[5]));
        asm("v_cvt_pk_bf16_f32 %0, %1, %2" : "=v"(b1) : "v"(pv[6]), "v"(pv[7]));
        asm("v_cvt_pk_bf16_f32 %0, %1, %2" : "=v"(c0) : "v"(pv[8]), "v"(pv[9]));
        asm("v_cvt_pk_bf16_f32 %0, %1, %2" : "=v"(c1) : "v"(pv[10]), "v"(pv[11]));
        asm("v_cvt_pk_bf16_f32 %0, %1, %2" : "=v"(d0) : "v"(pv[12]), "v"(pv[13]));
        asm("v_cvt_pk_bf16_f32 %0, %1, %2" : "=v"(d1) : "v"(pv[14]), "v"(pv[15]));
        asm("v_permlane32_swap_b32 %0, %1" : "+v"(a0), "+v"(b0));
        asm("v_permlane32_swap_b32 %0, %1" : "+v"(a1), "+v"(b1));
        asm("v_permlane32_swap_b32 %0, %1" : "+v"(c0), "+v"(d0));
        asm("v_permlane32_swap_b32 %0, %1" : "+v"(c1), "+v"(d1));
        u32x4 t0, t1;
        t0[0] = a0; t0[1] = a1; t0[2] = b0; t0[3] = b1;   // P[q][kv 0..15]
        t1[0] = c0; t1[1] = c1; t1[2] = d0; t1[3] = d1;   // P[q][kv 16..31]
        const short8 pa0 = __builtin_bit_cast(short8, t0);
        const short8 pa1 = __builtin_bit_cast(short8, t1);
        o0 = __builtin_amdgcn_mfma_f32_32x32x16_bf16(pa0, vf[0], o0, 0, 0, 0);
        o0 = __builtin_amdgcn_mfma_f32_32x32x16_bf16(pa1, vf[1], o0, 0, 0, 0);
        o1 = __builtin_amdgcn_mfma_f32_32x32x16_bf16(pa0, vf[2], o1, 0, 0, 0);
        o1 = __builtin_amdgcn_mfma_f32_32x32x16_bf16(pa1, vf[3], o1, 0, 0, 0);
    };

    auto dual = [&](const short8 (&kf)[4], const short8 (&vf)[4]) {
        body(kf, vf, qfA, oA0, oA1, lsvA, false);
        body(kf, vf, qfB, oB0, oB1, lsvB, false);
    };
    auto final_body = [&](const short8 (&kf)[4], const short8 (&vf)[4]) {
        if (par == 0) {
            body(kf, vf, qfA, oA0, oA1, lsvA, true);
            body(kf, vf, qfB, oB0, oB1, lsvB, false);
        } else {
            body(kf, vf, qfB, oB0, oB1, lsvB, true);
        }
    };

    kload(kA, par);
    vload(vA, par);
    int i = 0;
    for (; i + 2 <= P; i += 2) {
        kload(kB, par + 2 * (i + 1));
        vload(vB, par + 2 * (i + 1));
        dual(kA, vA);
        kload(kA, par + 2 * (i + 2));
        vload(vA, par + 2 * (i + 2));
        dual(kB, vB);
    }
    if (i < P) {
        kload(kB, par + 2 * P);
        vload(vB, par + 2 * P);
        dual(kA, vA);
        final_body(kB, vB);
    } else {
        final_body(kA, vA);
    }

    float lsA = (lsvA[0] + lsvA[1]) + (lsvA[2] + lsvA[3]);
    float lsB = (lsvB[0] + lsvB[1]) + (lsvB[2] + lsvB[3]);

    __shared__ float red[2][64][65];
    __shared__ float redl[2][64][2];
    if (par == 1) {
        float* dst = red[u][lane];
        #pragma unroll
        for (int rr = 0; rr < 16; ++rr) {
            dst[rr] = oA0[rr];
            dst[16 + rr] = oA1[rr];
            dst[32 + rr] = oB0[rr];
            dst[48 + rr] = oB1[rr];
        }
        redl[u][lane][0] = lsA;
        redl[u][lane][1] = lsB;
    }
    __syncthreads();
    if (par == 1) return;
    {
        const float* src = red[u][lane];
        #pragma unroll
        for (int rr = 0; rr < 16; ++rr) {
            oA0[rr] += src[rr];
            oA1[rr] += src[16 + rr];
            oB0[rr] += src[32 + rr];
            oB1[rr] += src[48 + rr];
        }
        lsA += redl[u][lane][0];
        lsB += redl[u][lane][1];
    }

    lsA += __shfl_xor(lsA, 32, 64);
    lsB += __shfl_xor(lsB, 32, 64);
    const float myInvA = 1.0f / lsA;
    const float myInvB = 1.0f / lsB;
    #pragma unroll
    for (int rr = 0; rr < 16; ++rr) {
        const int qrow = (rr & 3) + 8 * (rr >> 2) + 4 * hi;
        const float invA = __shfl(myInvA, qrow, 64);
        const float invB = __shfl(myInvB, qrow, 64);
        const size_t rowA = ((size_t)b * S + qbaseA + qrow) * 1024 + h * 64;
        const size_t rowB = ((size_t)b * S + qbaseB + qrow) * 1024 + h * 64;
        o[rowA + ln] = __float2bfloat16(oA0[rr] * invA);
        o[rowA + 32 + ln] = __float2bfloat16(oA1[rr] * invA);
        o[rowB + ln] = __float2bfloat16(oB0[rr] * invB);
        o[rowB + 32 + ln] = __float2bfloat16(oB1[rr] * invB);
    }
}

// -----------------------------------------------------------------------------
extern "C" void kernel_launch(void* const* d_in, const int* in_sizes, int n_in,
                              void* d_out, int out_size, void* d_ws, size_t ws_size,
                              hipStream_t stream) {
    const float* x = (const float*)d_in[0];     // [2,2048,1024]
    const float* Wqkv = (const float*)d_in[1];  // [1024,3072]
    const float* bqkv = (const float*)d_in[2];  // [3072]
    const float* Wo = (const float*)d_in[3];    // [1024,1024]
    const float* bo = (const float*)d_in[4];    // [1024]
    float* out = (float*)d_out;                 // [2,2048,1024] fp32
    char* ws = (char*)d_ws;

    // workspace layout (bytes), total 40 MB
    bf16* x_bf = (bf16*)(ws);                  //  8388608  [4096][1024]
    bf16* wqkv_t = (bf16*)(ws + 8388608);      //  6291456  [3072][1024]
    bf16* wo_t = (bf16*)(ws + 14680064);       //  2097152  [1024][1024]
    bf16* qb = (bf16*)(ws + 16777216);         //  8388608  [2,16,2048,64]
    bf16* kb = (bf16*)(ws + 25165824);         //  8388608  [2,16,2048,64]
    bf16* vtb = (bf16*)(ws + 33554432);        //  8388608  [2,16,64,2048]
    bf16* attn_o = x_bf;                       // alias: x_bf dead after gemm1

    prep_kernel<<<8192, 256, 0, stream>>>(x, x_bf, Wqkv, wqkv_t, Wo, wo_t);
    gemm_bt<1, 128><<<dim3(32, 24), 256, 0, stream>>>(
        x_bf, wqkv_t, bqkv, nullptr, qb, kb, vtb, 4096, 3072, 1024);
    attn_kernel<<<512, 256, 0, stream>>>(qb, kb, vtb, attn_o);
    gemm_bt<0, 64><<<dim3(32, 16), 256, 0, stream>>>(
        attn_o, wo_t, bo, out, nullptr, nullptr, nullptr, 4096, 1024, 1024);
}

// Round 19
// 106.549 us; speedup vs baseline: 1.0755x; 1.0755x over previous
//
#include <hip/hip_runtime.h>
#include <hip/hip_bf16.h>
#include <cstdint>
#include <cstddef>

// SelfAttention fused block, MI355X gfx950.
// Round 18: exp2f post-mortem — HIP exp2f() is the PRECISE ocml path (extra
// VALU per call); round-15's __expf() is native (v_mul log2e + v_exp).
// Minimal safe variant: QSCALE = 0.125 plain, body e = __expf(z) — same
// proven native intrinsic as the 41.9us round-15 body, minus only the
// z*0.125 pre-mul (16 VALU/body). No new intrinsics, no live-state change.
// Everything else round-15 verbatim (f32x4 lsv, 65-float merge, shfl reduce,
// dbuf 2-phase GEMMs). Base to beat: 106.8us (round-15 bench).
// Ledger: attn 41.9 (R15) | exp2f-precise 49 | ones-MFMA 48.1 | 4-way 63 |
//         uniform 64 | 3PF BUG.  QKV dbuf ~37 | 2-bar 43.6 | BK64swz 56.

using bf16 = __hip_bfloat16;
typedef __attribute__((ext_vector_type(8))) short short8;
typedef __attribute__((ext_vector_type(4))) float f32x4;
typedef __attribute__((ext_vector_type(16))) float f32x16;
typedef __attribute__((ext_vector_type(4))) unsigned int u32x4;

#define QSCALE 0.125f  // folded softmax scale: P = exp(Qs.K) = exp(0.125 Q.K)

__device__ __forceinline__ unsigned short f2b(float f) {
    bf16 h = __float2bfloat16(f);
    return *reinterpret_cast<unsigned short*>(&h);
}

__device__ __forceinline__ void async16(const void* g, void* l) {
    __builtin_amdgcn_global_load_lds(
        (const __attribute__((address_space(1))) void*)g,
        (__attribute__((address_space(3))) void*)l, 16, 0, 0);
}

// ---------------- K1: fused prep: x fp32->bf16, Wqkv^T (q-scaled), Wo^T ------
__global__ __launch_bounds__(256) void prep_kernel(
    const float* __restrict__ x, bf16* __restrict__ x_bf,
    const float* __restrict__ Wqkv, bf16* __restrict__ wqkv_t,
    const float* __restrict__ Wo, bf16* __restrict__ wo_t) {
    const int bid = blockIdx.x;
    const int tid = threadIdx.x;
    if (bid < 4096) {  // cvt: 1M float4
        const int i = bid * 256 + tid;
        const float4 v = reinterpret_cast<const float4*>(x)[i];
        ushort4 o;
        o.x = f2b(v.x); o.y = f2b(v.y); o.z = f2b(v.z); o.w = f2b(v.w);
        reinterpret_cast<ushort4*>(x_bf)[i] = o;
        return;
    }
    __shared__ float tile[32][33];
    const float* in;
    bf16* out;
    int K, N, n0, k0;
    if (bid < 4096 + 3072) {
        const int blk = bid - 4096;
        in = Wqkv; out = wqkv_t; K = 1024; N = 3072;
        n0 = (blk % 96) * 32; k0 = (blk / 96) * 32;
    } else {
        const int blk = bid - 7168;
        in = Wo; out = wo_t; K = 1024; N = 1024;
        n0 = (blk % 32) * 32; k0 = (blk / 32) * 32;
    }
    // q-part of Wqkv (output cols 0..1023) pre-scaled by QSCALE
    const float scl =
        (bid >= 4096 && bid < 7168 && ((bid - 4096) % 96) < 32) ? QSCALE : 1.0f;
    const int tx = tid & 31, ty = tid >> 5;  // (32,8)
    #pragma unroll
    for (int i = 0; i < 32; i += 8)
        tile[ty + i][tx] = in[(size_t)(k0 + ty + i) * N + n0 + tx];
    __syncthreads();
    #pragma unroll
    for (int i = 0; i < 32; i += 8)
        out[(size_t)(n0 + ty + i) * K + k0 + tx] =
            __float2bfloat16(tile[tx][ty + i] * scl);
}

// --- K3/K5: 128xBN BK=32 linear-LDS bf16 MFMA GEMM, dbuf prefetch, B^T in ----
template <int EPI, int BN>
__global__ __launch_bounds__(256) void gemm_bt(
    const bf16* __restrict__ A,   // [M][K] bf16
    const bf16* __restrict__ Bt,  // [N][K] bf16
    const float* __restrict__ bias,  // [N] fp32
    float* __restrict__ Cf,          // EPI==0: [M][N] fp32
    bf16* __restrict__ qd, bf16* __restrict__ kd, bf16* __restrict__ vtd,
    int M, int N, int K) {
    constexpr int NFR = BN / 32;  // B frags per wave (wave n-span = BN/2)
    __shared__ bf16 As[2][128 * 32];
    __shared__ bf16 Bs[2][BN * 32];
    const int t = threadIdx.x;
    const int lane = t & 63;
    const int lr = lane & 15, lg = lane >> 4;
    const int wave = t >> 6;
    const int wr = wave >> 1, wc = wave & 1;  // 2x2 waves
    const int m0 = blockIdx.x * 128, n0 = blockIdx.y * BN;

    const bf16* aSrc = A + (size_t)(m0 + (t >> 2)) * K + (t & 3) * 8;
    const bf16* bSrc = Bt + (size_t)(n0 + (t >> 2)) * K + (t & 3) * 8;
    const size_t rowStep = (size_t)64 * K;

    auto stage = [&](int buf, int k0) {
        async16(aSrc + k0, &As[buf][t * 8]);
        async16(aSrc + rowStep + k0, &As[buf][2048 + t * 8]);
        async16(bSrc + k0, &Bs[buf][t * 8]);
        if constexpr (BN == 128)
            async16(bSrc + rowStep + k0, &Bs[buf][2048 + t * 8]);
    };

    f32x4 acc[4][NFR] = {};

    stage(0, 0);
    __syncthreads();

    int cur = 0;
    for (int k0 = 0; k0 < K; k0 += 32) {
        if (k0 + 32 < K) stage(cur ^ 1, k0 + 32);
        short8 af[4], bfr[NFR];
        #pragma unroll
        for (int i = 0; i < 4; ++i)
            af[i] = *reinterpret_cast<const short8*>(
                &As[cur][(wr * 64 + i * 16 + lr) * 32 + lg * 8]);
        #pragma unroll
        for (int i = 0; i < NFR; ++i)
            bfr[i] = *reinterpret_cast<const short8*>(
                &Bs[cur][(wc * (BN / 2) + i * 16 + lr) * 32 + lg * 8]);
        #pragma unroll
        for (int mi = 0; mi < 4; ++mi)
            #pragma unroll
            for (int ni = 0; ni < NFR; ++ni)
                acc[mi][ni] = __builtin_amdgcn_mfma_f32_16x16x32_bf16(
                    af[mi], bfr[ni], acc[mi][ni], 0, 0, 0);
        __syncthreads();
        cur ^= 1;
    }

    #pragma unroll
    for (int mi = 0; mi < 4; ++mi) {
        #pragma unroll
        for (int ni = 0; ni < NFR; ++ni) {
            const int rowb = m0 + wr * 64 + mi * 16 + lg * 4;
            const int col = n0 + wc * (BN / 2) + ni * 16 + lr;
            if constexpr (EPI == 0) {
                #pragma unroll
                for (int r = 0; r < 4; ++r)
                    Cf[(size_t)(rowb + r) * N + col] = acc[mi][ni][r] + bias[col];
            } else {
                float bs = bias[col];
                if (col < 1024) bs *= QSCALE;  // q-bias matches scaled weights
                const int part = col >> 10;      // 0=q 1=k 2=v
                const int within = col & 1023;
                const int h = within >> 6, d = within & 63;
                const int b = rowb >> 11, s0 = rowb & 2047;
                const int bh = b * 16 + h;
                if (part == 2) {  // v^T: 4 consecutive s -> ushort4
                    ushort4 pk;
                    pk.x = f2b(acc[mi][ni][0] + bs);
                    pk.y = f2b(acc[mi][ni][1] + bs);
                    pk.z = f2b(acc[mi][ni][2] + bs);
                    pk.w = f2b(acc[mi][ni][3] + bs);
                    *reinterpret_cast<ushort4*>(
                        &vtd[((size_t)bh * 64 + d) * 2048 + s0]) = pk;
                } else {
                    bf16* dst = (part == 0) ? qd : kd;
                    #pragma unroll
                    for (int r = 0; r < 4; ++r)
                        dst[((size_t)bh * 2048 + s0 + r) * 64 + d] =
                            __float2bfloat16(acc[mi][ni][r] + bs);
                }
            }
        }
    }
}

// ---------------- K4: causal flash attention (R15 body, no pre-mul) ----------
// grid 512 (1-D, XCD-pinned), block 256 = 4 waves = 2 units x 2 parities.
// Decode: res=f&7, m=f>>3, grp=m>>4, bh=res+8*grp, bxr=m&15,
//   bx=(grp&2)?(15-bxr):bxr  -> co-resident pair (f, f+256) complementary
//   heavy+light per CU (measured-optimal; do not touch).
// Body = round-15 verbatim except e = __expf(z) (Q pre-scaled by 0.125).
__global__ __launch_bounds__(256, 2) void attn_kernel(const bf16* __restrict__ q,
                                                      const bf16* __restrict__ k,
                                                      const bf16* __restrict__ vt,
                                                      bf16* __restrict__ o) {
    const int S = 2048;
    const int f = blockIdx.x;
    const int res = f & 7, m = f >> 3;
    const int grp = m >> 4;
    const int bh = res + 8 * grp;
    const int bxr = m & 15;
    const int bx = (grp & 2) ? (15 - bxr) : bxr;
    const int b = bh >> 4, h = bh & 15;
    const int w = threadIdx.x >> 6;
    const int u = w >> 1, par = w & 1;
    const int lane = threadIdx.x & 63;
    const int ln = lane & 31;
    const int hi = lane >> 5;
    const int P = 2 * (15 - bx) + u;     // 0..31
    const int qbaseA = P * 64;
    const int qbaseB = P * 64 + 32;

    const bf16* qp = q + (size_t)bh * S * 64;
    const bf16* kp = k + (size_t)bh * S * 64;
    const bf16* vp = vt + (size_t)bh * 64 * S;

    short8 qfA[4], qfB[4];
    #pragma unroll
    for (int i = 0; i < 4; ++i) {
        qfA[i] = *reinterpret_cast<const short8*>(
            &qp[(size_t)(qbaseA + ln) * 64 + i * 16 + hi * 8]);
        qfB[i] = *reinterpret_cast<const short8*>(
            &qp[(size_t)(qbaseB + ln) * 64 + i * 16 + hi * 8]);
    }

    f32x16 oA0 = {}, oA1 = {}, oB0 = {}, oB1 = {};
    f32x4 lsvA = {0.f, 0.f, 0.f, 0.f}, lsvB = {0.f, 0.f, 0.f, 0.f};

    short8 kA[4], kB[4], vA[4], vB[4];

    auto kload = [&](short8 (&kf)[4], int tile) {
        const bf16* base = &kp[(size_t)(tile * 32 + ln) * 64 + hi * 8];
        #pragma unroll
        for (int i = 0; i < 4; ++i)
            kf[i] = *reinterpret_cast<const short8*>(base + i * 16);
    };
    auto vload = [&](short8 (&vf)[4], int tile) {
        #pragma unroll
        for (int dblk = 0; dblk < 2; ++dblk)
            #pragma unroll
            for (int half = 0; half < 2; ++half)
                vf[dblk * 2 + half] = *reinterpret_cast<const short8*>(
                    &vp[(size_t)(dblk * 32 + ln) * S + tile * 32 + half * 16 +
                        hi * 8]);
    };

    auto body = [&](const short8 (&kf)[4], const short8 (&vf)[4],
                    const short8 (&qf)[4], f32x16& o0, f32x16& o1, f32x4& lsv,
                    bool diag) {
        f32x16 z0 = {}, z1 = {};
        z0 = __builtin_amdgcn_mfma_f32_32x32x16_bf16(kf[0], qf[0], z0, 0, 0, 0);
        z0 = __builtin_amdgcn_mfma_f32_32x32x16_bf16(kf[1], qf[1], z0, 0, 0, 0);
        z1 = __builtin_amdgcn_mfma_f32_32x32x16_bf16(kf[2], qf[2], z1, 0, 0, 0);
        z1 = __builtin_amdgcn_mfma_f32_32x32x16_bf16(kf[3], qf[3], z1, 0, 0, 0);
        const f32x16 z = z0 + z1;
        f32x16 pv;
        #pragma unroll
        for (int rr = 0; rr < 16; ++rr) {
            const int kreg = (rr & 3) + 8 * (rr >> 2) + 4 * hi;
            float e = __expf(z[rr]);         // Q pre-scaled by 0.125
            if (diag && (kreg > ln)) e = 0.f;
            pv[rr] = e;
            lsv[rr & 3] += e;
        }
        unsigned a0, a1, b0, b1, c0, c1, d0, d1;
        asm("v_cvt_pk_bf16_f32 %0, %1, %2" : "=v"(a0) : "v"(pv[0]), "v"(pv[1]));
        asm("v_cvt_pk_bf16_f32 %0, %1, %2" : "=v"(a1) : "v"(pv[2]), "v"(pv[3]));
        asm("v_cvt_pk_bf16_f32 %0, %1, %2" : "=v"(b0) : "v"(pv[4]), "v"(pv[5]));
        asm("v_cvt_pk_bf16_f32 %0, %1, %2" : "=v"(b1) : "v"(pv[6]), "v"(pv[7]));
        asm("v_cvt_pk_bf16_f32 %0, %1, %2" : "=v"(c0) : "v"(pv[8]), "v"(pv[9]));
        asm("v_cvt_pk_bf16_f32 %0, %1, %2" : "=v"(c1) : "v"(pv[10]), "v"(pv[11]));
        asm("v_cvt_pk_bf16_f32 %0, %1, %2" : "=v"(d0) : "v"(pv[12]), "v"(pv[13]));
        asm("v_cvt_pk_bf16_f32 %0, %1, %2" : "=v"(d1) : "v"(pv[14]), "v"(pv[15]));
        asm("v_permlane32_swap_b32 %0, %1" : "+v"(a0), "+v"(b0));
        asm("v_permlane32_swap_b32 %0, %1" : "+v"(a1), "+v"(b1));
        asm("v_permlane32_swap_b32 %0, %1" : "+v"(c0), "+v"(d0));
        asm("v_permlane32_swap_b32 %0, %1" : "+v"(c1), "+v"(d1));
        u32x4 t0, t1;
        t0[0] = a0; t0[1] = a1; t0[2] = b0; t0[3] = b1;   // P[q][kv 0..15]
        t1[0] = c0; t1[1] = c1; t1[2] = d0; t1[3] = d1;   // P[q][kv 16..31]
        const short8 pa0 = __builtin_bit_cast(short8, t0);
        const short8 pa1 = __builtin_bit_cast(short8, t1);
        o0 = __builtin_amdgcn_mfma_f32_32x32x16_bf16(pa0, vf[0], o0, 0, 0, 0);
        o0 = __builtin_amdgcn_mfma_f32_32x32x16_bf16(pa1, vf[1], o0, 0, 0, 0);
        o1 = __builtin_amdgcn_mfma_f32_32x32x16_bf16(pa0, vf[2], o1, 0, 0, 0);
        o1 = __builtin_amdgcn_mfma_f32_32x32x16_bf16(pa1, vf[3], o1, 0, 0, 0);
    };

    auto dual = [&](const short8 (&kf)[4], const short8 (&vf)[4]) {
        body(kf, vf, qfA, oA0, oA1, lsvA, false);
        body(kf, vf, qfB, oB0, oB1, lsvB, false);
    };
    auto final_body = [&](const short8 (&kf)[4], const short8 (&vf)[4]) {
        if (par == 0) {
            body(kf, vf, qfA, oA0, oA1, lsvA, true);
            body(kf, vf, qfB, oB0, oB1, lsvB, false);
        } else {
            body(kf, vf, qfB, oB0, oB1, lsvB, true);
        }
    };

    kload(kA, par);
    vload(vA, par);
    int i = 0;
    for (; i + 2 <= P; i += 2) {
        kload(kB, par + 2 * (i + 1));
        vload(vB, par + 2 * (i + 1));
        dual(kA, vA);
        kload(kA, par + 2 * (i + 2));
        vload(vA, par + 2 * (i + 2));
        dual(kB, vB);
    }
    if (i < P) {
        kload(kB, par + 2 * P);
        vload(vB, par + 2 * P);
        dual(kA, vA);
        final_body(kB, vB);
    } else {
        final_body(kA, vA);
    }

    float lsA = (lsvA[0] + lsvA[1]) + (lsvA[2] + lsvA[3]);
    float lsB = (lsvB[0] + lsvB[1]) + (lsvB[2] + lsvB[3]);

    __shared__ float red[2][64][65];
    __shared__ float redl[2][64][2];
    if (par == 1) {
        float* dst = red[u][lane];
        #pragma unroll
        for (int rr = 0; rr < 16; ++rr) {
            dst[rr] = oA0[rr];
            dst[16 + rr] = oA1[rr];
            dst[32 + rr] = oB0[rr];
            dst[48 + rr] = oB1[rr];
        }
        redl[u][lane][0] = lsA;
        redl[u][lane][1] = lsB;
    }
    __syncthreads();
    if (par == 1) return;
    {
        const float* src = red[u][lane];
        #pragma unroll
        for (int rr = 0; rr < 16; ++rr) {
            oA0[rr] += src[rr];
            oA1[rr] += src[16 + rr];
            oB0[rr] += src[32 + rr];
            oB1[rr] += src[48 + rr];
        }
        lsA += redl[u][lane][0];
        lsB += redl[u][lane][1];
    }

    lsA += __shfl_xor(lsA, 32, 64);
    lsB += __shfl_xor(lsB, 32, 64);
    const float myInvA = 1.0f / lsA;
    const float myInvB = 1.0f / lsB;
    #pragma unroll
    for (int rr = 0; rr < 16; ++rr) {
        const int qrow = (rr & 3) + 8 * (rr >> 2) + 4 * hi;
        const float invA = __shfl(myInvA, qrow, 64);
        const float invB = __shfl(myInvB, qrow, 64);
        const size_t rowA = ((size_t)b * S + qbaseA + qrow) * 1024 + h * 64;
        const size_t rowB = ((size_t)b * S + qbaseB + qrow) * 1024 + h * 64;
        o[rowA + ln] = __float2bfloat16(oA0[rr] * invA);
        o[rowA + 32 + ln] = __float2bfloat16(oA1[rr] * invA);
        o[rowB + ln] = __float2bfloat16(oB0[rr] * invB);
        o[rowB + 32 + ln] = __float2bfloat16(oB1[rr] * invB);
    }
}

// -----------------------------------------------------------------------------
extern "C" void kernel_launch(void* const* d_in, const int* in_sizes, int n_in,
                              void* d_out, int out_size, void* d_ws, size_t ws_size,
                              hipStream_t stream) {
    const float* x = (const float*)d_in[0];     // [2,2048,1024]
    const float* Wqkv = (const float*)d_in[1];  // [1024,3072]
    const float* bqkv = (const float*)d_in[2];  // [3072]
    const float* Wo = (const float*)d_in[3];    // [1024,1024]
    const float* bo = (const float*)d_in[4];    // [1024]
    float* out = (float*)d_out;                 // [2,2048,1024] fp32
    char* ws = (char*)d_ws;

    // workspace layout (bytes), total 40 MB
    bf16* x_bf = (bf16*)(ws);                  //  8388608  [4096][1024]
    bf16* wqkv_t = (bf16*)(ws + 8388608);      //  6291456  [3072][1024]
    bf16* wo_t = (bf16*)(ws + 14680064);       //  2097152  [1024][1024]
    bf16* qb = (bf16*)(ws + 16777216);         //  8388608  [2,16,2048,64]
    bf16* kb = (bf16*)(ws + 25165824);         //  8388608  [2,16,2048,64]
    bf16* vtb = (bf16*)(ws + 33554432);        //  8388608  [2,16,64,2048]
    bf16* attn_o = x_bf;                       // alias: x_bf dead after gemm1

    prep_kernel<<<8192, 256, 0, stream>>>(x, x_bf, Wqkv, wqkv_t, Wo, wo_t);
    gemm_bt<1, 128><<<dim3(32, 24), 256, 0, stream>>>(
        x_bf, wqkv_t, bqkv, nullptr, qb, kb, vtb, 4096, 3072, 1024);
    attn_kernel<<<512, 256, 0, stream>>>(qb, kb, vtb, attn_o);
    gemm_bt<0, 64><<<dim3(32, 16), 256, 0, stream>>>(
        attn_o, wo_t, bo, out, nullptr, nullptr, nullptr, 4096, 1024, 1024);
}

// Round 20
// 106.124 us; speedup vs baseline: 1.0798x; 1.0040x over previous
//
#include <hip/hip_runtime.h>
#include <hip/hip_bf16.h>
#include <cstdint>
#include <cstddef>

// SelfAttention fused block, MI355X gfx950.
// Round 19 (final tuning round): best-known config (106.5us measured) + one
// monotone micro-change: attn QK^T uses a SINGLE 4-deep MFMA chain (m119:
// dependent chains >=2 sustain full rate) instead of z0/z1 + 16 v_add_f32.
// Deletes 32 VALU cyc/dual-body and one live f32x16 (-16 peak VGPR pressure
// at the 128 cap). Same sync, same memory pattern, same instruction types.
// Session ledger (attn): R8 2-way 43.1 -> prescale 41.7 | exp2f 49 |
//   onesMFMA 48.1 | 4-way 63 | uniform 64 | 3PF BUG.
// (GEMM): dbuf BK32 ~37 | 2-bar 43.6 | BK64swz 56 | BN64 61 | 8ph-256^2 68.7.

using bf16 = __hip_bfloat16;
typedef __attribute__((ext_vector_type(8))) short short8;
typedef __attribute__((ext_vector_type(4))) float f32x4;
typedef __attribute__((ext_vector_type(16))) float f32x16;
typedef __attribute__((ext_vector_type(4))) unsigned int u32x4;

#define QSCALE 0.125f  // folded softmax scale: P = exp(Qs.K) = exp(0.125 Q.K)

__device__ __forceinline__ unsigned short f2b(float f) {
    bf16 h = __float2bfloat16(f);
    return *reinterpret_cast<unsigned short*>(&h);
}

__device__ __forceinline__ void async16(const void* g, void* l) {
    __builtin_amdgcn_global_load_lds(
        (const __attribute__((address_space(1))) void*)g,
        (__attribute__((address_space(3))) void*)l, 16, 0, 0);
}

// ---------------- K1: fused prep: x fp32->bf16, Wqkv^T (q-scaled), Wo^T ------
__global__ __launch_bounds__(256) void prep_kernel(
    const float* __restrict__ x, bf16* __restrict__ x_bf,
    const float* __restrict__ Wqkv, bf16* __restrict__ wqkv_t,
    const float* __restrict__ Wo, bf16* __restrict__ wo_t) {
    const int bid = blockIdx.x;
    const int tid = threadIdx.x;
    if (bid < 4096) {  // cvt: 1M float4
        const int i = bid * 256 + tid;
        const float4 v = reinterpret_cast<const float4*>(x)[i];
        ushort4 o;
        o.x = f2b(v.x); o.y = f2b(v.y); o.z = f2b(v.z); o.w = f2b(v.w);
        reinterpret_cast<ushort4*>(x_bf)[i] = o;
        return;
    }
    __shared__ float tile[32][33];
    const float* in;
    bf16* out;
    int K, N, n0, k0;
    if (bid < 4096 + 3072) {
        const int blk = bid - 4096;
        in = Wqkv; out = wqkv_t; K = 1024; N = 3072;
        n0 = (blk % 96) * 32; k0 = (blk / 96) * 32;
    } else {
        const int blk = bid - 7168;
        in = Wo; out = wo_t; K = 1024; N = 1024;
        n0 = (blk % 32) * 32; k0 = (blk / 32) * 32;
    }
    // q-part of Wqkv (output cols 0..1023) pre-scaled by QSCALE
    const float scl =
        (bid >= 4096 && bid < 7168 && ((bid - 4096) % 96) < 32) ? QSCALE : 1.0f;
    const int tx = tid & 31, ty = tid >> 5;  // (32,8)
    #pragma unroll
    for (int i = 0; i < 32; i += 8)
        tile[ty + i][tx] = in[(size_t)(k0 + ty + i) * N + n0 + tx];
    __syncthreads();
    #pragma unroll
    for (int i = 0; i < 32; i += 8)
        out[(size_t)(n0 + ty + i) * K + k0 + tx] =
            __float2bfloat16(tile[tx][ty + i] * scl);
}

// --- K3/K5: 128xBN BK=32 linear-LDS bf16 MFMA GEMM, dbuf prefetch, B^T in ----
template <int EPI, int BN>
__global__ __launch_bounds__(256) void gemm_bt(
    const bf16* __restrict__ A,   // [M][K] bf16
    const bf16* __restrict__ Bt,  // [N][K] bf16
    const float* __restrict__ bias,  // [N] fp32
    float* __restrict__ Cf,          // EPI==0: [M][N] fp32
    bf16* __restrict__ qd, bf16* __restrict__ kd, bf16* __restrict__ vtd,
    int M, int N, int K) {
    constexpr int NFR = BN / 32;  // B frags per wave (wave n-span = BN/2)
    __shared__ bf16 As[2][128 * 32];
    __shared__ bf16 Bs[2][BN * 32];
    const int t = threadIdx.x;
    const int lane = t & 63;
    const int lr = lane & 15, lg = lane >> 4;
    const int wave = t >> 6;
    const int wr = wave >> 1, wc = wave & 1;  // 2x2 waves
    const int m0 = blockIdx.x * 128, n0 = blockIdx.y * BN;

    const bf16* aSrc = A + (size_t)(m0 + (t >> 2)) * K + (t & 3) * 8;
    const bf16* bSrc = Bt + (size_t)(n0 + (t >> 2)) * K + (t & 3) * 8;
    const size_t rowStep = (size_t)64 * K;

    auto stage = [&](int buf, int k0) {
        async16(aSrc + k0, &As[buf][t * 8]);
        async16(aSrc + rowStep + k0, &As[buf][2048 + t * 8]);
        async16(bSrc + k0, &Bs[buf][t * 8]);
        if constexpr (BN == 128)
            async16(bSrc + rowStep + k0, &Bs[buf][2048 + t * 8]);
    };

    f32x4 acc[4][NFR] = {};

    stage(0, 0);
    __syncthreads();

    int cur = 0;
    for (int k0 = 0; k0 < K; k0 += 32) {
        if (k0 + 32 < K) stage(cur ^ 1, k0 + 32);
        short8 af[4], bfr[NFR];
        #pragma unroll
        for (int i = 0; i < 4; ++i)
            af[i] = *reinterpret_cast<const short8*>(
                &As[cur][(wr * 64 + i * 16 + lr) * 32 + lg * 8]);
        #pragma unroll
        for (int i = 0; i < NFR; ++i)
            bfr[i] = *reinterpret_cast<const short8*>(
                &Bs[cur][(wc * (BN / 2) + i * 16 + lr) * 32 + lg * 8]);
        #pragma unroll
        for (int mi = 0; mi < 4; ++mi)
            #pragma unroll
            for (int ni = 0; ni < NFR; ++ni)
                acc[mi][ni] = __builtin_amdgcn_mfma_f32_16x16x32_bf16(
                    af[mi], bfr[ni], acc[mi][ni], 0, 0, 0);
        __syncthreads();
        cur ^= 1;
    }

    #pragma unroll
    for (int mi = 0; mi < 4; ++mi) {
        #pragma unroll
        for (int ni = 0; ni < NFR; ++ni) {
            const int rowb = m0 + wr * 64 + mi * 16 + lg * 4;
            const int col = n0 + wc * (BN / 2) + ni * 16 + lr;
            if constexpr (EPI == 0) {
                #pragma unroll
                for (int r = 0; r < 4; ++r)
                    Cf[(size_t)(rowb + r) * N + col] = acc[mi][ni][r] + bias[col];
            } else {
                float bs = bias[col];
                if (col < 1024) bs *= QSCALE;  // q-bias matches scaled weights
                const int part = col >> 10;      // 0=q 1=k 2=v
                const int within = col & 1023;
                const int h = within >> 6, d = within & 63;
                const int b = rowb >> 11, s0 = rowb & 2047;
                const int bh = b * 16 + h;
                if (part == 2) {  // v^T: 4 consecutive s -> ushort4
                    ushort4 pk;
                    pk.x = f2b(acc[mi][ni][0] + bs);
                    pk.y = f2b(acc[mi][ni][1] + bs);
                    pk.z = f2b(acc[mi][ni][2] + bs);
                    pk.w = f2b(acc[mi][ni][3] + bs);
                    *reinterpret_cast<ushort4*>(
                        &vtd[((size_t)bh * 64 + d) * 2048 + s0]) = pk;
                } else {
                    bf16* dst = (part == 0) ? qd : kd;
                    #pragma unroll
                    for (int r = 0; r < 4; ++r)
                        dst[((size_t)bh * 2048 + s0 + r) * 64 + d] =
                            __float2bfloat16(acc[mi][ni][r] + bs);
                }
            }
        }
    }
}

// ---------------- K4: causal flash attention (R19 body, single z-chain) ------
// grid 512 (1-D, XCD-pinned), block 256 = 4 waves = 2 units x 2 parities.
// Decode: res=f&7, m=f>>3, grp=m>>4, bh=res+8*grp, bxr=m&15,
//   bx=(grp&2)?(15-bxr):bxr  -> co-resident pair (f, f+256) complementary
//   heavy+light per CU (measured-optimal; do not touch).
// Body: 4 QK MFMAs in ONE dependent chain (full-rate per m119), no z-merge.
__global__ __launch_bounds__(256, 2) void attn_kernel(const bf16* __restrict__ q,
                                                      const bf16* __restrict__ k,
                                                      const bf16* __restrict__ vt,
                                                      bf16* __restrict__ o) {
    const int S = 2048;
    const int f = blockIdx.x;
    const int res = f & 7, m = f >> 3;
    const int grp = m >> 4;
    const int bh = res + 8 * grp;
    const int bxr = m & 15;
    const int bx = (grp & 2) ? (15 - bxr) : bxr;
    const int b = bh >> 4, h = bh & 15;
    const int w = threadIdx.x >> 6;
    const int u = w >> 1, par = w & 1;
    const int lane = threadIdx.x & 63;
    const int ln = lane & 31;
    const int hi = lane >> 5;
    const int P = 2 * (15 - bx) + u;     // 0..31
    const int qbaseA = P * 64;
    const int qbaseB = P * 64 + 32;

    const bf16* qp = q + (size_t)bh * S * 64;
    const bf16* kp = k + (size_t)bh * S * 64;
    const bf16* vp = vt + (size_t)bh * 64 * S;

    short8 qfA[4], qfB[4];
    #pragma unroll
    for (int i = 0; i < 4; ++i) {
        qfA[i] = *reinterpret_cast<const short8*>(
            &qp[(size_t)(qbaseA + ln) * 64 + i * 16 + hi * 8]);
        qfB[i] = *reinterpret_cast<const short8*>(
            &qp[(size_t)(qbaseB + ln) * 64 + i * 16 + hi * 8]);
    }

    f32x16 oA0 = {}, oA1 = {}, oB0 = {}, oB1 = {};
    f32x4 lsvA = {0.f, 0.f, 0.f, 0.f}, lsvB = {0.f, 0.f, 0.f, 0.f};

    short8 kA[4], kB[4], vA[4], vB[4];

    auto kload = [&](short8 (&kf)[4], int tile) {
        const bf16* base = &kp[(size_t)(tile * 32 + ln) * 64 + hi * 8];
        #pragma unroll
        for (int i = 0; i < 4; ++i)
            kf[i] = *reinterpret_cast<const short8*>(base + i * 16);
    };
    auto vload = [&](short8 (&vf)[4], int tile) {
        #pragma unroll
        for (int dblk = 0; dblk < 2; ++dblk)
            #pragma unroll
            for (int half = 0; half < 2; ++half)
                vf[dblk * 2 + half] = *reinterpret_cast<const short8*>(
                    &vp[(size_t)(dblk * 32 + ln) * S + tile * 32 + half * 16 +
                        hi * 8]);
    };

    auto body = [&](const short8 (&kf)[4], const short8 (&vf)[4],
                    const short8 (&qf)[4], f32x16& o0, f32x16& o1, f32x4& lsv,
                    bool diag) {
        f32x16 z = {};
        z = __builtin_amdgcn_mfma_f32_32x32x16_bf16(kf[0], qf[0], z, 0, 0, 0);
        z = __builtin_amdgcn_mfma_f32_32x32x16_bf16(kf[1], qf[1], z, 0, 0, 0);
        z = __builtin_amdgcn_mfma_f32_32x32x16_bf16(kf[2], qf[2], z, 0, 0, 0);
        z = __builtin_amdgcn_mfma_f32_32x32x16_bf16(kf[3], qf[3], z, 0, 0, 0);
        f32x16 pv;
        #pragma unroll
        for (int rr = 0; rr < 16; ++rr) {
            const int kreg = (rr & 3) + 8 * (rr >> 2) + 4 * hi;
            float e = __expf(z[rr]);         // Q pre-scaled by 0.125
            if (diag && (kreg > ln)) e = 0.f;
            pv[rr] = e;
            lsv[rr & 3] += e;
        }
        unsigned a0, a1, b0, b1, c0, c1, d0, d1;
        asm("v_cvt_pk_bf16_f32 %0, %1, %2" : "=v"(a0) : "v"(pv[0]), "v"(pv[1]));
        asm("v_cvt_pk_bf16_f32 %0, %1, %2" : "=v"(a1) : "v"(pv[2]), "v"(pv[3]));
        asm("v_cvt_pk_bf16_f32 %0, %1, %2" : "=v"(b0) : "v"(pv[4]), "v"(pv[5]));
        asm("v_cvt_pk_bf16_f32 %0, %1, %2" : "=v"(b1) : "v"(pv[6]), "v"(pv[7]));
        asm("v_cvt_pk_bf16_f32 %0, %1, %2" : "=v"(c0) : "v"(pv[8]), "v"(pv[9]));
        asm("v_cvt_pk_bf16_f32 %0, %1, %2" : "=v"(c1) : "v"(pv[10]), "v"(pv[11]));
        asm("v_cvt_pk_bf16_f32 %0, %1, %2" : "=v"(d0) : "v"(pv[12]), "v"(pv[13]));
        asm("v_cvt_pk_bf16_f32 %0, %1, %2" : "=v"(d1) : "v"(pv[14]), "v"(pv[15]));
        asm("v_permlane32_swap_b32 %0, %1" : "+v"(a0), "+v"(b0));
        asm("v_permlane32_swap_b32 %0, %1" : "+v"(a1), "+v"(b1));
        asm("v_permlane32_swap_b32 %0, %1" : "+v"(c0), "+v"(d0));
        asm("v_permlane32_swap_b32 %0, %1" : "+v"(c1), "+v"(d1));
        u32x4 t0, t1;
        t0[0] = a0; t0[1] = a1; t0[2] = b0; t0[3] = b1;   // P[q][kv 0..15]
        t1[0] = c0; t1[1] = c1; t1[2] = d0; t1[3] = d1;   // P[q][kv 16..31]
        const short8 pa0 = __builtin_bit_cast(short8, t0);
        const short8 pa1 = __builtin_bit_cast(short8, t1);
        o0 = __builtin_amdgcn_mfma_f32_32x32x16_bf16(pa0, vf[0], o0, 0, 0, 0);
        o0 = __builtin_amdgcn_mfma_f32_32x32x16_bf16(pa1, vf[1], o0, 0, 0, 0);
        o1 = __builtin_amdgcn_mfma_f32_32x32x16_bf16(pa0, vf[2], o1, 0, 0, 0);
        o1 = __builtin_amdgcn_mfma_f32_32x32x16_bf16(pa1, vf[3], o1, 0, 0, 0);
    };

    auto dual = [&](const short8 (&kf)[4], const short8 (&vf)[4]) {
        body(kf, vf, qfA, oA0, oA1, lsvA, false);
        body(kf, vf, qfB, oB0, oB1, lsvB, false);
    };
    auto final_body = [&](const short8 (&kf)[4], const short8 (&vf)[4]) {
        if (par == 0) {
            body(kf, vf, qfA, oA0, oA1, lsvA, true);
            body(kf, vf, qfB, oB0, oB1, lsvB, false);
        } else {
            body(kf, vf, qfB, oB0, oB1, lsvB, true);
        }
    };

    kload(kA, par);
    vload(vA, par);
    int i = 0;
    for (; i + 2 <= P; i += 2) {
        kload(kB, par + 2 * (i + 1));
        vload(vB, par + 2 * (i + 1));
        dual(kA, vA);
        kload(kA, par + 2 * (i + 2));
        vload(vA, par + 2 * (i + 2));
        dual(kB, vB);
    }
    if (i < P) {
        kload(kB, par + 2 * P);
        vload(vB, par + 2 * P);
        dual(kA, vA);
        final_body(kB, vB);
    } else {
        final_body(kA, vA);
    }

    float lsA = (lsvA[0] + lsvA[1]) + (lsvA[2] + lsvA[3]);
    float lsB = (lsvB[0] + lsvB[1]) + (lsvB[2] + lsvB[3]);

    __shared__ float red[2][64][65];
    __shared__ float redl[2][64][2];
    if (par == 1) {
        float* dst = red[u][lane];
        #pragma unroll
        for (int rr = 0; rr < 16; ++rr) {
            dst[rr] = oA0[rr];
            dst[16 + rr] = oA1[rr];
            dst[32 + rr] = oB0[rr];
            dst[48 + rr] = oB1[rr];
        }
        redl[u][lane][0] = lsA;
        redl[u][lane][1] = lsB;
    }
    __syncthreads();
    if (par == 1) return;
    {
        const float* src = red[u][lane];
        #pragma unroll
        for (int rr = 0; rr < 16; ++rr) {
            oA0[rr] += src[rr];
            oA1[rr] += src[16 + rr];
            oB0[rr] += src[32 + rr];
            oB1[rr] += src[48 + rr];
        }
        lsA += redl[u][lane][0];
        lsB += redl[u][lane][1];
    }

    lsA += __shfl_xor(lsA, 32, 64);
    lsB += __shfl_xor(lsB, 32, 64);
    const float myInvA = 1.0f / lsA;
    const float myInvB = 1.0f / lsB;
    #pragma unroll
    for (int rr = 0; rr < 16; ++rr) {
        const int qrow = (rr & 3) + 8 * (rr >> 2) + 4 * hi;
        const float invA = __shfl(myInvA, qrow, 64);
        const float invB = __shfl(myInvB, qrow, 64);
        const size_t rowA = ((size_t)b * S + qbaseA + qrow) * 1024 + h * 64;
        const size_t rowB = ((size_t)b * S + qbaseB + qrow) * 1024 + h * 64;
        o[rowA + ln] = __float2bfloat16(oA0[rr] * invA);
        o[rowA + 32 + ln] = __float2bfloat16(oA1[rr] * invA);
        o[rowB + ln] = __float2bfloat16(oB0[rr] * invB);
        o[rowB + 32 + ln] = __float2bfloat16(oB1[rr] * invB);
    }
}

// -----------------------------------------------------------------------------
extern "C" void kernel_launch(void* const* d_in, const int* in_sizes, int n_in,
                              void* d_out, int out_size, void* d_ws, size_t ws_size,
                              hipStream_t stream) {
    const float* x = (const float*)d_in[0];     // [2,2048,1024]
    const float* Wqkv = (const float*)d_in[1];  // [1024,3072]
    const float* bqkv = (const float*)d_in[2];  // [3072]
    const float* Wo = (const float*)d_in[3];    // [1024,1024]
    const float* bo = (const float*)d_in[4];    // [1024]
    float* out = (float*)d_out;                 // [2,2048,1024] fp32
    char* ws = (char*)d_ws;

    // workspace layout (bytes), total 40 MB
    bf16* x_bf = (bf16*)(ws);                  //  8388608  [4096][1024]
    bf16* wqkv_t = (bf16*)(ws + 8388608);      //  6291456  [3072][1024]
    bf16* wo_t = (bf16*)(ws + 14680064);       //  2097152  [1024][1024]
    bf16* qb = (bf16*)(ws + 16777216);         //  8388608  [2,16,2048,64]
    bf16* kb = (bf16*)(ws + 25165824);         //  8388608  [2,16,2048,64]
    bf16* vtb = (bf16*)(ws + 33554432);        //  8388608  [2,16,64,2048]
    bf16* attn_o = x_bf;                       // alias: x_bf dead after gemm1

    prep_kernel<<<8192, 256, 0, stream>>>(x, x_bf, Wqkv, wqkv_t, Wo, wo_t);
    gemm_bt<1, 128><<<dim3(32, 24), 256, 0, stream>>>(
        x_bf, wqkv_t, bqkv, nullptr, qb, kb, vtb, 4096, 3072, 1024);
    attn_kernel<<<512, 256, 0, stream>>>(qb, kb, vtb, attn_o);
    gemm_bt<0, 64><<<dim3(32, 16), 256, 0, stream>>>(
        attn_o, wo_t, bo, out, nullptr, nullptr, nullptr, 4096, 1024, 1024);
}